// Round 1
// baseline (3810.641 us; speedup 1.0000x reference)
//
#include <hip/hip_runtime.h>
#include <cstdint>
#include <cmath>

// Problem constants (from reference)
#define BB 16
#define TT 2048
#define DD 1024
#define HH 512
// GEMM: M = B*T = 32768, N = 2*H*3 = 3072, K = D = 1024

// ---------------------------------------------------------------------------
// Kernel 0: permute W (D,2,H,3) -> Wp (D,2,3,H) so GEMM B-loads and scan U
// reads are coalesced (h innermost).
// Wp[d, z, k, h] = W[d, z, h, k]
// ---------------------------------------------------------------------------
__global__ __launch_bounds__(256) void permuteW(const float* __restrict__ W,
                                                float* __restrict__ Wp) {
    int idx = blockIdx.x * 256 + threadIdx.x;  // output index
    if (idx >= DD * 3072) return;
    int d    = idx / 3072;
    int rem  = idx % 3072;
    int z    = rem / 1536;
    int rem2 = rem % 1536;
    int k    = rem2 / 512;
    int h    = rem2 % 512;
    Wp[idx] = W[d * 3072 + z * 1536 + h * 3 + k];
}

// ---------------------------------------------------------------------------
// Kernel 1: fp32 vector GEMM, C[M,N] = A[M,K] @ B[K,N]
// 128x128 block tile, BK=16, 256 threads, 8x8 per-thread micro-tile.
// ---------------------------------------------------------------------------
#define BM 128
#define BN 128
#define BK 16

__global__ __launch_bounds__(256) void gemm_f32(const float* __restrict__ A,
                                                const float* __restrict__ Bp,
                                                float* __restrict__ C) {
    const int N = 3072, K = DD;
    __shared__ float As[BK][BM];  // A tile stored transposed: As[k][m]
    __shared__ float Bs[BK][BN];

    const int t  = threadIdx.x;
    const int m0 = blockIdx.x * BM;
    const int n0 = blockIdx.y * BN;

    float acc[8][8];
#pragma unroll
    for (int i = 0; i < 8; i++)
#pragma unroll
        for (int j = 0; j < 8; j++) acc[i][j] = 0.f;

    const int tm8 = (t >> 4) << 3;  // (t/16)*8 : row group 0..120
    const int tn8 = (t & 15) << 3;  // (t%16)*8 : col group 0..120

    const float* Aptr = A + (size_t)m0 * K;
    const float* Bptr = Bp + n0;

    for (int k0 = 0; k0 < K; k0 += BK) {
        // Load A tile: 128 rows x 16 cols = 512 float4, 2 per thread.
#pragma unroll
        for (int i = 0; i < 2; i++) {
            int idx = t + i * 256;  // 0..511
            int r   = idx >> 2;     // 0..127
            int c4  = idx & 3;      // 0..3
            const float4 v =
                *(const float4*)(Aptr + (size_t)r * K + k0 + c4 * 4);
            As[c4 * 4 + 0][r] = v.x;
            As[c4 * 4 + 1][r] = v.y;
            As[c4 * 4 + 2][r] = v.z;
            As[c4 * 4 + 3][r] = v.w;
        }
        // Load B tile: 16 rows x 128 cols = 512 float4, 2 per thread.
#pragma unroll
        for (int i = 0; i < 2; i++) {
            int idx = t + i * 256;
            int kk  = idx >> 5;  // 0..15
            int n4  = idx & 31;  // 0..31
            const float4 v =
                *(const float4*)(Bptr + (size_t)(k0 + kk) * N + n4 * 4);
            *(float4*)&Bs[kk][n4 * 4] = v;
        }
        __syncthreads();

#pragma unroll
        for (int kk = 0; kk < BK; kk++) {
            float a[8], b[8];
            *(float4*)&a[0] = *(const float4*)&As[kk][tm8];
            *(float4*)&a[4] = *(const float4*)&As[kk][tm8 + 4];
            *(float4*)&b[0] = *(const float4*)&Bs[kk][tn8];
            *(float4*)&b[4] = *(const float4*)&Bs[kk][tn8 + 4];
#pragma unroll
            for (int i = 0; i < 8; i++)
#pragma unroll
                for (int j = 0; j < 8; j++)
                    acc[i][j] = fmaf(a[i], b[j], acc[i][j]);
        }
        __syncthreads();
    }

    // Epilogue: coalesced float4 stores.
    float* Cp = C + (size_t)(m0 + tm8) * N + n0 + tn8;
#pragma unroll
    for (int i = 0; i < 8; i++) {
        *(float4*)(Cp + (size_t)i * N)     = *(float4*)&acc[i][0];
        *(float4*)(Cp + (size_t)i * N + 4) = *(float4*)&acc[i][4];
    }
}

// ---------------------------------------------------------------------------
// Kernel 2: SRU elementwise recurrence. One thread per (b, z, h) channel.
// U layout: U[(b*T + t)*3072 + z*1536 + gate*512 + h], gate: 0=g, 1=f, 2=r.
// z=0: forward over t; z=1: backward over t (matches reference reversal).
// out: d_out[0 .. B*T*1024) = h outputs (b,t,z*512+h);
//      d_out[B*T*1024 ..]   = c_last (b, z*512+h).
// ---------------------------------------------------------------------------
__global__ __launch_bounds__(64) void sru_scan(const float* __restrict__ U,
                                               const float* __restrict__ x,
                                               const float* __restrict__ bias,
                                               float* __restrict__ out) {
    int ch = blockIdx.x * 64 + threadIdx.x;  // 0..16383
    int b  = ch >> 10;
    int zh = ch & 1023;
    int z  = zh >> 9;
    int h  = zh & 511;

    const float bf = bias[z * 1024 + h];        // bias[z][0][h]
    const float br = bias[z * 1024 + 512 + h];  // bias[z][1][h]

    const float* Ub = U + (size_t)b * TT * 3072 + z * 1536 + h;
    const float* xb = x + (size_t)b * TT * 1024 + z * 512 + h;
    float* ob       = out + (size_t)b * TT * 1024 + z * 512 + h;

    int tt   = (z == 0) ? 0 : TT - 1;
    int step = (z == 0) ? 1 : -1;

    float c = 0.f;
    for (int n = 0; n < TT; n++, tt += step) {
        size_t o = (size_t)tt * 3072;
        float g  = Ub[o];
        float fp = Ub[o + 512];
        float rp = Ub[o + 1024];
        float xv = xb[(size_t)tt * 1024];
        float f  = 1.f / (1.f + __expf(-(fp + bf)));
        float r  = 1.f / (1.f + __expf(-(rp + br)));
        c        = f * c + (1.f - f) * g;
        float hv = r * tanhf(c) + (1.f - r) * xv;
        ob[(size_t)tt * 1024] = hv;
    }

    // c_last
    out[(size_t)BB * TT * 1024 + b * 1024 + z * 512 + h] = c;
}

// ---------------------------------------------------------------------------
extern "C" void kernel_launch(void* const* d_in, const int* in_sizes, int n_in,
                              void* d_out, int out_size, void* d_ws,
                              size_t ws_size, hipStream_t stream) {
    const float* x    = (const float*)d_in[0];
    const float* W    = (const float*)d_in[1];
    const float* bias = (const float*)d_in[2];
    float* out        = (float*)d_out;

    float* Wp = (float*)d_ws;                       // 1024*3072 f32 = 12.6 MB
    float* U  = Wp + (size_t)DD * 3072;             // 32768*3072 f32 = 402 MB

    permuteW<<<(DD * 3072 + 255) / 256, 256, 0, stream>>>(W, Wp);

    dim3 grid(BB * TT / BM, 3072 / BN);             // (256, 24)
    gemm_f32<<<grid, 256, 0, stream>>>(x, Wp, U);

    sru_scan<<<256, 64, 0, stream>>>(U, x, bias, out);
}

// Round 5
// 1015.840 us; speedup vs baseline: 3.7512x; 3.7512x over previous
//
#include <hip/hip_runtime.h>
#include <cstdint>

typedef unsigned int uint;
typedef unsigned short ushort;
typedef __attribute__((ext_vector_type(8))) __bf16 bf16x8;
typedef __attribute__((ext_vector_type(4))) float f32x4;
typedef __attribute__((ext_vector_type(4))) ushort us4;

#define BB 16
#define TT 2048
#define DD 1024
#define HH 512
// GEMM: M = 32768, N = 3072, K = 1024

// ---------------------------------------------------------------------------
// helpers
// ---------------------------------------------------------------------------
__device__ inline ushort f2bf(float f) {
    uint u = __float_as_uint(f);
    u += 0x7FFF + ((u >> 16) & 1);  // RNE
    return (ushort)(u >> 16);
}
__device__ inline float bf2f(ushort b) {
    return __uint_as_float(((uint)b) << 16);
}
__device__ inline float sigm(float x) { return 1.f / (1.f + __expf(-x)); }

__device__ inline void gload16(const void* g, void* l) {
    __builtin_amdgcn_global_load_lds(
        (const __attribute__((address_space(1))) uint*)g,
        (__attribute__((address_space(3))) uint*)l, 16, 0, 0);
}

// ---------------------------------------------------------------------------
// W (D,2,H,3) f32 -> Bth, Btl bf16 [N=3072][K=1024] (transposed, hi/lo split)
// n = z*1536 + gate*512 + h ;  Bt[n][d] = W[d][z][h][gate]
// ---------------------------------------------------------------------------
__global__ __launch_bounds__(256) void convert_W(const float* __restrict__ W,
                                                 ushort* __restrict__ Bth,
                                                 ushort* __restrict__ Btl) {
    int idx = blockIdx.x * 256 + threadIdx.x;  // 0 .. 3,145,727
    int d   = idx & 1023;
    int n   = idx >> 10;
    int z    = n / 1536;
    int rem  = n % 1536;
    int gate = rem >> 9;
    int h    = rem & 511;
    float w    = W[(size_t)d * 3072 + z * 1536 + h * 3 + gate];
    ushort whi = f2bf(w);
    Bth[idx]   = whi;
    Btl[idx]   = f2bf(w - bf2f(whi));
}

// ---------------------------------------------------------------------------
// split-bf16 MFMA GEMM with fused A conversion.
// C[M][3072] ~= (Ah+Al)(Bh+Bl)  (Ah·Bh + Ah·Bl + Al·Bh; Al·Bl dropped)
// 128x128 tile, BK=32, 256 threads = 4 waves (2x2), each wave 64x64 = 4x4
// 16x16x32 fragments, 3 MFMA per fragment pair.
//
// LDS: 4 arrays of [128 rows][32 k] bf16 (8 KB each): Ah | Al | Bh | Bl.
// 16B k-chunks XOR-swizzled by ((row>>1)&3). A is reg-staged from f32 x
// (convert hi/lo in-register, swizzled ds_write). B is global_load_lds
// direct with the swizzle pre-applied to the per-lane global source.
// Read side applies the same XOR -> logically cancels; ds_read_b128 covers
// each bank exactly 2x per 16-lane quarter (bandwidth-optimal).
// ---------------------------------------------------------------------------
__global__ __launch_bounds__(256, 2) void gemm_bf16split(
    const float* __restrict__ x, const ushort* __restrict__ Bth,
    const ushort* __restrict__ Btl, float* __restrict__ C) {
    __shared__ ushort lds[4 * 128 * 32];  // 32 KB

    const int t    = threadIdx.x;
    const int w    = t >> 6;
    const int lane = t & 63;
    const size_t m0 = (size_t)blockIdx.x * 128;
    const size_t n0 = (size_t)blockIdx.y * 128;
    const int wm = w >> 1, wn = w & 1;

    f32x4 acc[4][4];
#pragma unroll
    for (int i = 0; i < 4; i++)
#pragma unroll
        for (int j = 0; j < 4; j++) acc[i][j] = (f32x4)(0.f);

    // B staging: per array 2 calls; row = w*32 + c*16 + (lane>>2),
    // physical chunk = lane&3, logical = (lane&3) ^ ((row>>1)&3)
    const int srow  = w * 32 + (lane >> 2);
    const int kphys = lane & 3;

    // frag read: row (lane&15); logical chunk = lane>>4,
    // physical = (lane>>4) ^ ((row>>1)&3), and (row>>1)&3 == ((lane&15)>>1)&3
    const int frow  = lane & 15;
    const int fkoff = (((lane >> 4) ^ ((frow >> 1) & 3)) << 3);  // ushort off

    for (int k0 = 0; k0 < 1024; k0 += 32) {
        // ---- A tile: load 128x32 f32 of x into regs (4 float4/thread) ----
        float4 xv[4];
#pragma unroll
        for (int p = 0; p < 4; p++) {
            int ridx = p * 256 + t;  // 0..1023
            int row  = ridx >> 3;    // 0..127
            int kq   = ridx & 7;     // float4 index
            xv[p] = *(const float4*)(x + (m0 + row) * 1024 + k0 + kq * 4);
        }
        // ---- B tiles: async global->LDS, pre-swizzled source ----
#pragma unroll
        for (int arr = 0; arr < 2; arr++) {
            const ushort* G = arr ? Btl : Bth;
#pragma unroll
            for (int c = 0; c < 2; c++) {
                const int row = srow + c * 16;
                const int kcl = kphys ^ ((row >> 1) & 3);
                const ushort* src = G + ((n0 + row) << 10) + k0 + (kcl << 3);
                char* dst = (char*)lds + (2 + arr) * 8192 +
                            (w * 32 + c * 16) * 64 + lane * 16;
                gload16(src, dst);
            }
        }
        // ---- convert A to hi/lo bf16, swizzled ds_write (8B each) ----
#pragma unroll
        for (int p = 0; p < 4; p++) {
            int ridx = p * 256 + t;
            int row  = ridx >> 3;
            int kq   = ridx & 7;
            int off  = row * 64 + (((kq >> 1) ^ ((row >> 1) & 3)) << 4) +
                       ((kq & 1) << 3);
            float vf[4] = {xv[p].x, xv[p].y, xv[p].z, xv[p].w};
            us4 hi, lo;
#pragma unroll
            for (int j = 0; j < 4; j++) {
                ushort h = f2bf(vf[j]);
                hi[j]    = h;
                lo[j]    = f2bf(vf[j] - bf2f(h));
            }
            *(us4*)((char*)lds + off)        = hi;
            *(us4*)((char*)lds + 8192 + off) = lo;
        }
        __syncthreads();  // drains lgkm (ds_write) + vm (global_load_lds)

        bf16x8 fa[4], fal[4], fb[4], fbl[4];
#pragma unroll
        for (int i = 0; i < 4; i++) {
            const int ra = (wm * 64 + i * 16 + frow) * 32;
            const int rb = (wn * 64 + i * 16 + frow) * 32;
            fa[i]  = *(const bf16x8*)&lds[0 * 4096 + ra + fkoff];
            fal[i] = *(const bf16x8*)&lds[1 * 4096 + ra + fkoff];
            fb[i]  = *(const bf16x8*)&lds[2 * 4096 + rb + fkoff];
            fbl[i] = *(const bf16x8*)&lds[3 * 4096 + rb + fkoff];
        }
#pragma unroll
        for (int i = 0; i < 4; i++)
#pragma unroll
            for (int j = 0; j < 4; j++) {
                acc[i][j] = __builtin_amdgcn_mfma_f32_16x16x32_bf16(
                    fa[i], fb[j], acc[i][j], 0, 0, 0);
                acc[i][j] = __builtin_amdgcn_mfma_f32_16x16x32_bf16(
                    fa[i], fbl[j], acc[i][j], 0, 0, 0);
                acc[i][j] = __builtin_amdgcn_mfma_f32_16x16x32_bf16(
                    fal[i], fb[j], acc[i][j], 0, 0, 0);
            }
        __syncthreads();  // protect LDS before next stage
    }

    // epilogue: C/D layout col=lane&15 (n), row=(lane>>4)*4+reg (m)
    const int ccol = lane & 15;
    const int crow = (lane >> 4) * 4;
#pragma unroll
    for (int i = 0; i < 4; i++) {
        const size_t mrow = m0 + wm * 64 + i * 16 + crow;
#pragma unroll
        for (int j = 0; j < 4; j++) {
            const size_t ncol = n0 + wn * 64 + j * 16 + ccol;
            float* Cp = C + mrow * 3072 + ncol;
#pragma unroll
            for (int r = 0; r < 4; r++) Cp[(size_t)r * 3072] = acc[i][j][r];
        }
    }
}

// ---------------------------------------------------------------------------
// Scan: 16384 channels (b,z,h), T=2048 split into 16 chunks of 128.
// U[(b*T+t)*3072 + z*1536 + gate*512 + h], gate 0=g 1=f 2=r.
// logical step n; physical t = z ? T-1-n : n.
// ---------------------------------------------------------------------------
#define SCH 16384
#define NCH 16
#define CL 128

__global__ __launch_bounds__(256) void scanA(const float* __restrict__ U,
                                             const float* __restrict__ bias,
                                             float* __restrict__ F,
                                             float* __restrict__ Cp) {
    int idx = blockIdx.x * 256 + threadIdx.x;  // 0..262143
    int ch  = idx & (SCH - 1);
    int s   = idx >> 14;
    int b = ch >> 10, z = (ch >> 9) & 1, h = ch & 511;
    float bf = bias[z * 1024 + h];
    const float* Ub = U + (size_t)b * TT * 3072 + z * 1536 + h;
    float c = 0.f, Fa = 1.f;
    for (int q = 0; q < CL; q++) {
        int n = s * CL + q;
        int t = z ? (TT - 1 - n) : n;
        size_t o = (size_t)t * 3072;
        float g = Ub[o], fp = Ub[o + 512];
        float f = sigm(fp + bf);
        c  = f * c + (1.f - f) * g;
        Fa *= f;
    }
    F[s * SCH + ch]  = Fa;
    Cp[s * SCH + ch] = c;
}

__global__ __launch_bounds__(256) void scanB(const float* __restrict__ F,
                                             const float* __restrict__ Cp,
                                             float* __restrict__ cstart) {
    int ch = blockIdx.x * 256 + threadIdx.x;  // 16384
    float c = 0.f;
    for (int s = 0; s < NCH; s++) {
        cstart[s * SCH + ch] = c;
        c = F[s * SCH + ch] * c + Cp[s * SCH + ch];
    }
}

__global__ __launch_bounds__(256) void scanC(const float* __restrict__ U,
                                             const float* __restrict__ x,
                                             const float* __restrict__ bias,
                                             const float* __restrict__ cstart,
                                             float* __restrict__ out) {
    int idx = blockIdx.x * 256 + threadIdx.x;
    int ch  = idx & (SCH - 1);
    int s   = idx >> 14;
    int b = ch >> 10, z = (ch >> 9) & 1, h = ch & 511;
    float bf = bias[z * 1024 + h];
    float br = bias[z * 1024 + 512 + h];
    const float* Ub = U + (size_t)b * TT * 3072 + z * 1536 + h;
    const float* xb = x + (size_t)b * TT * 1024 + z * 512 + h;
    float* ob       = out + (size_t)b * TT * 1024 + z * 512 + h;
    float c = cstart[s * SCH + ch];
    for (int q = 0; q < CL; q++) {
        int n = s * CL + q;
        int t = z ? (TT - 1 - n) : n;
        size_t o = (size_t)t * 3072;
        float g = Ub[o], fp = Ub[o + 512], rp = Ub[o + 1024];
        float xv = xb[(size_t)t * 1024];
        float f = sigm(fp + bf);
        float r = sigm(rp + br);
        c = f * c + (1.f - f) * g;
        float e  = __expf(2.f * c);
        float th = 1.f - 2.f / (e + 1.f);  // tanh(c), inf-safe
        ob[(size_t)t * 1024] = r * th + (1.f - r) * xv;
    }
    if (s == NCH - 1)
        out[(size_t)BB * TT * 1024 + b * 1024 + z * 512 + h] = c;
}

// ---------------------------------------------------------------------------
// Workspace budget (total 415,236,096 B — identical to the round-1 kernel
// that ran successfully; round-3's 552 MB is the suspected crash cause):
//   U   : [0, 402,653,184)
//   Bth : [402,653,184, 408,944,640)
//   Btl : [408,944,640, 415,236,096)
//   F/Cp/cst alias over Bth (dead after GEMM): 3 x 1,048,576 floats
// ---------------------------------------------------------------------------
extern "C" void kernel_launch(void* const* d_in, const int* in_sizes, int n_in,
                              void* d_out, int out_size, void* d_ws,
                              size_t ws_size, hipStream_t stream) {
    const float* x    = (const float*)d_in[0];
    const float* W    = (const float*)d_in[1];
    const float* bias = (const float*)d_in[2];
    float* out        = (float*)d_out;

    char* ws    = (char*)d_ws;
    float* U    = (float*)ws;
    ushort* Bth = (ushort*)(ws + 402653184UL);
    ushort* Btl = (ushort*)(ws + 408944640UL);
    float* F    = (float*)(ws + 402653184UL);  // alias (B dead after GEMM)
    float* Cp   = (float*)(ws + 406847488UL);
    float* cst  = (float*)(ws + 411041792UL);

    convert_W<<<12288, 256, 0, stream>>>(W, Bth, Btl);

    dim3 grid(256, 24);
    gemm_bf16split<<<grid, 256, 0, stream>>>(x, Bth, Btl, U);

    scanA<<<1024, 256, 0, stream>>>(U, bias, F, Cp);
    scanB<<<64, 256, 0, stream>>>(F, Cp, cst);
    scanC<<<1024, 256, 0, stream>>>(U, x, bias, cst, out);
}